// Round 8
// baseline (409.967 us; speedup 1.0000x reference)
//
#include <hip/hip_runtime.h>

#define N_NODES 1024
#define C_CH    128
#define N_ELEM  10
#define K3      11
#define W3PM    1040                 // padded symmetric-cubic floats per slot
#define SU2OFF  49920                // float offset of SU2 region in ws (4*1040*12)

// ---------- kernel A0: element/channel-independent symmetrized U ----------
__global__ __launch_bounds__(256) void precompute_kernel(
    const float* __restrict__ U03, const float* __restrict__ U02,
    const float* __restrict__ U13, const float* __restrict__ U12,
    float* __restrict__ ws)
{
  const int t = blockIdx.x * 256 + threadIdx.x;
  if (t < 4160) {                    // SU3 rows: [m][j(padded 1040)][12]
    const int m = t / W3PM;
    const int j = t - m * W3PM;
    int a = 0, b = 0, off = 0;
    bool fnd = false;
    for (a = 0; a < 16 && !fnd; ++a) {
      for (b = 0; b <= a; ++b) {
        const int rl = ((b >> 2) + 1) << 2;
        if (j < off + rl) { fnd = true; break; }
        off += rl;
      }
      if (fnd) break;
    }
    const int cc = j - off;
    float out[12];
    #pragma unroll
    for (int k = 0; k < 12; ++k) out[k] = 0.f;
    if (cc <= b) {
      const float* U3 = (m == 0) ? U03 : (U13 + (size_t)(m - 1) * 45056);
      int bases[6]; int np = 0;
      if (a == b && b == cc) {
        bases[np++] = ((a * 16 + a) * 16 + a) * K3;
      } else if (a == b) {
        bases[np++] = ((a * 16 + a) * 16 + cc) * K3;
        bases[np++] = ((a * 16 + cc) * 16 + a) * K3;
        bases[np++] = ((cc * 16 + a) * 16 + a) * K3;
      } else if (b == cc) {
        bases[np++] = ((a * 16 + b) * 16 + b) * K3;
        bases[np++] = ((b * 16 + a) * 16 + b) * K3;
        bases[np++] = ((b * 16 + b) * 16 + a) * K3;
      } else {
        bases[np++] = ((a * 16 + b) * 16 + cc) * K3;
        bases[np++] = ((a * 16 + cc) * 16 + b) * K3;
        bases[np++] = ((b * 16 + a) * 16 + cc) * K3;
        bases[np++] = ((b * 16 + cc) * 16 + a) * K3;
        bases[np++] = ((cc * 16 + a) * 16 + b) * K3;
        bases[np++] = ((cc * 16 + b) * 16 + a) * K3;
      }
      for (int p = 0; p < np; ++p) {
        const float* src = U3 + bases[p];
        #pragma unroll
        for (int k = 0; k < K3; ++k) out[k] += src[k];
      }
    }
    float* dst = ws + (size_t)t * 12;
    *(float4*)&dst[0] = make_float4(out[0], out[1], out[2],  out[3]);
    *(float4*)&dst[4] = make_float4(out[4], out[5], out[6],  out[7]);
    *(float4*)&dst[8] = make_float4(out[8], out[9], out[10], out[11]);
  } else if (t < 4704) {             // SU2 rows: [m][q(136)][4]
    const int u = t - 4160;
    const int m = u / 136;
    const int q = u - m * 136;
    int a = 0, b = q;
    while (b > a) { b -= (a + 1); ++a; }
    const float* U2 = (m == 0) ? U02 : (U12 + (size_t)(m - 1) * 1024);
    const float* p1 = U2 + (a * 16 + b) * 4;
    float4 r = make_float4(p1[0], p1[1], p1[2], p1[3]);
    if (a != b) {
      const float* p2 = U2 + (b * 16 + a) * 4;
      r.x += p2[0]; r.y += p2[1]; r.z += p2[2]; r.w += p2[3];
    }
    ((float4*)(ws + SU2OFF))[u] = r;
  }
}

// ---------- kernel B: per-(e,c) contraction ----------
__global__ __launch_bounds__(256, 5) void sym_contract_kernel(
    const float* __restrict__ node_feats,   // [N, C, 16]
    const float* __restrict__ node_attrs,   // [N, 10]
    const float* __restrict__ W03, const float* __restrict__ W02,
    const float* __restrict__ W01, const float* __restrict__ W13,
    const float* __restrict__ W12, const float* __restrict__ W11,
    const float* __restrict__ U01, const float* __restrict__ U11,
    const float* __restrict__ ws,           // SU3 | SU2
    float* __restrict__ feats_out)          // [N, C*4] pre-linear (= d_out)
{
  __shared__ float W3c[4 * W3PM];           // 16.6 KB
  __shared__ float T2c[4 * 136];
  __shared__ float T1s[64];
  __shared__ unsigned short nodelist[N_NODES];
  __shared__ float wrow[32];
  __shared__ int cnt;

  const int e   = blockIdx.x / C_CH;
  const int c   = blockIdx.x % C_CH;
  const int tid = threadIdx.x;

  if (tid == 0) cnt = 0;
  if (tid < 32) {
    float v;
    if (tid < 11)       v = W03[(e * K3 + tid) * C_CH + c];
    else if (tid < 15)  v = W02[(e * 4 + (tid - 11)) * C_CH + c];
    else if (tid == 15) v = W01[e * C_CH + c];
    else if (tid < 27)  v = W13[(e * K3 + (tid - 16)) * C_CH + c];
    else if (tid < 31)  v = W12[(e * 4 + (tid - 27)) * C_CH + c];
    else                v = W11[e * C_CH + c];
    wrow[tid] = v;
  }
  __syncthreads();

  // node list for this element
  for (int nd = tid; nd < N_NODES; nd += 256)
    if (node_attrs[nd * N_ELEM + e] > 0.5f)
      nodelist[atomicAdd(&cnt, 1)] = (unsigned short)nd;

  // --- W3c = SU3 . wk  (coalesced 48B rows, lane-consecutive LDS writes) ---
  for (int ms = 0; ms < 4; ++ms) {
    const int wb = (ms == 0) ? 0 : 16;
    const float w0 = wrow[wb],     w1 = wrow[wb + 1], w2 = wrow[wb + 2];
    const float w3 = wrow[wb + 3], w4 = wrow[wb + 4], w5 = wrow[wb + 5];
    const float w6 = wrow[wb + 6], w7 = wrow[wb + 7], w8 = wrow[wb + 8];
    const float w9 = wrow[wb + 9], wA = wrow[wb + 10];
    for (int j = tid; j < W3PM; j += 256) {
      const float* r = ws + ((size_t)ms * W3PM + j) * 12;
      const float4 r0 = *(const float4*)&r[0];
      const float4 r1 = *(const float4*)&r[4];
      const float4 r2 = *(const float4*)&r[8];
      float acc =       r0.x * w0;
      acc = fmaf(r0.y, w1, acc); acc = fmaf(r0.z, w2, acc);
      acc = fmaf(r0.w, w3, acc); acc = fmaf(r1.x, w4, acc);
      acc = fmaf(r1.y, w5, acc); acc = fmaf(r1.z, w6, acc);
      acc = fmaf(r1.w, w7, acc); acc = fmaf(r2.x, w8, acc);
      acc = fmaf(r2.y, w9, acc); acc = fmaf(r2.z, wA, acc);
      W3c[ms * W3PM + j] = acc;
    }
  }
  // --- T2c = SU2 . w2 ---
  const float4* SU2 = (const float4*)(ws + SU2OFF);
  for (int ms = 0; ms < 4; ++ms) {
    const int wb = (ms == 0) ? 11 : 27;
    const float q0 = wrow[wb], q1 = wrow[wb + 1], q2 = wrow[wb + 2], q3 = wrow[wb + 3];
    for (int q = tid; q < 136; q += 256) {
      const float4 r = SU2[ms * 136 + q];
      float acc = r.x * q0;
      acc = fmaf(r.y, q1, acc); acc = fmaf(r.z, q2, acc); acc = fmaf(r.w, q3, acc);
      T2c[ms * 136 + q] = acc;
    }
  }
  if (tid < 64) {
    const int mm = tid >> 4, i1 = tid & 15;
    T1s[tid] = (mm == 0) ? U01[i1] * wrow[15] : U11[(mm - 1) * 16 + i1] * wrow[31];
  }
  __syncthreads();

  // --- phase B: wave = m slot, lane = node; triangular Horner, dual chains ---
  const int m    = tid >> 6;
  const int lane = tid & 63;
  const float* W3m = W3c + m * W3PM;
  const float* T2m = T2c + m * 136;
  const float* T1m = T1s + m * 16;
  const int total = cnt;

  for (int base = 0; base < total; base += 64) {
    const int idx     = base + lane;
    const bool active = idx < total;
    const int nd = nodelist[active ? idx : 0];
    const float* xr = node_feats + ((size_t)nd * C_CH + c) * 16;
    float xs[16];                            // static-index only -> registers
    *(float4*)&xs[0]  = ((const float4*)xr)[0];
    *(float4*)&xs[4]  = ((const float4*)xr)[1];
    *(float4*)&xs[8]  = ((const float4*)xr)[2];
    *(float4*)&xs[12] = ((const float4*)xr)[3];

    float acc0 = 0.f, acc1 = 0.f;
    int woff = 0, tp = 0;                    // unroll-folded running offsets
    #pragma unroll
    for (int a = 0; a < 16; ++a) {
      float i1a = T1m[a], i1b = 0.f;         // dual chains over b
      #pragma unroll
      for (int b = 0; b <= a; ++b) {
        float in2 = T2m[tp];
        #pragma unroll
        for (int q = 0; q <= (b >> 2); ++q) {
          const float4 w4 = *(const float4*)&W3m[woff + 4 * q];   // broadcast
          in2 = fmaf(w4.x, xs[4 * q + 0], in2);
          in2 = fmaf(w4.y, xs[4 * q + 1], in2);
          in2 = fmaf(w4.z, xs[4 * q + 2], in2);
          in2 = fmaf(w4.w, xs[4 * q + 3], in2);
        }
        if (b & 1) i1b = fmaf(in2, xs[b], i1b);
        else       i1a = fmaf(in2, xs[b], i1a);
        woff += ((b >> 2) + 1) << 2;
        ++tp;
      }
      const float in1 = i1a + i1b;
      if (a & 1) acc1 = fmaf(in1, xs[a], acc1);
      else       acc0 = fmaf(in1, xs[a], acc0);
    }
    if (active)
      feats_out[(size_t)nd * 512 + c * 4 + m] = acc0 + acc1;
  }
}

__global__ __launch_bounds__(256) void linear_kernel(
    const float* __restrict__ sc,
    const float* __restrict__ lin0,
    const float* __restrict__ lin1,
    float* __restrict__ io)             // d_out, in-place per-row
{
  __shared__ float f[512];              // [c][m]
  const int b   = blockIdx.x;
  const int tid = threadIdx.x;
  const float* row = io + (size_t)b * 512;
  if (tid < 128) ((float4*)f)[tid] = ((const float4*)row)[tid];
  __syncthreads();
  const float inv_sqrt_c = 0.088388347648318447f;   // 1/sqrt(128)
  #pragma unroll
  for (int rep = 0; rep < 2; ++rep) {
    const int o = tid + rep * 256;
    float acc = 0.f;
    if (o < 128) {
      const int fo = o;
      #pragma unroll 4
      for (int ci = 0; ci < 128; ++ci) acc = fmaf(f[ci * 4], lin0[ci * 128 + fo], acc);
    } else {
      const int oo = o - 128;
      const int fo = oo / 3;
      const int dd = oo - fo * 3;
      #pragma unroll 4
      for (int ci = 0; ci < 128; ++ci) acc = fmaf(f[ci * 4 + 1 + dd], lin1[ci * 128 + fo], acc);
    }
    io[(size_t)b * 512 + o] = fmaf(acc, inv_sqrt_c, sc[(size_t)b * 512 + o]);
  }
}

extern "C" void kernel_launch(void* const* d_in, const int* in_sizes, int n_in,
                              void* d_out, int out_size, void* d_ws, size_t ws_size,
                              hipStream_t stream) {
  const float* node_feats = (const float*)d_in[0];
  const float* sc         = (const float*)d_in[1];
  const float* node_attrs = (const float*)d_in[2];
  const float* U01  = (const float*)d_in[3];
  const float* W01  = (const float*)d_in[4];
  const float* U02  = (const float*)d_in[5];
  const float* W02  = (const float*)d_in[6];
  const float* U03  = (const float*)d_in[7];
  const float* W03  = (const float*)d_in[8];
  const float* lin0 = (const float*)d_in[9];
  const float* U11  = (const float*)d_in[10];
  const float* W11  = (const float*)d_in[11];
  const float* U12  = (const float*)d_in[12];
  const float* W12  = (const float*)d_in[13];
  const float* U13  = (const float*)d_in[14];
  const float* W13  = (const float*)d_in[15];
  const float* lin1 = (const float*)d_in[16];
  float* out = (float*)d_out;
  float* ws  = (float*)d_ws;

  precompute_kernel<<<19, 256, 0, stream>>>(U03, U02, U13, U12, ws);
  sym_contract_kernel<<<N_ELEM * C_CH, 256, 0, stream>>>(
      node_feats, node_attrs,
      W03, W02, W01, W13, W12, W11, U01, U11, ws, out);
  linear_kernel<<<N_NODES, 256, 0, stream>>>(sc, lin0, lin1, out);
}

// Round 9
// 142.137 us; speedup vs baseline: 2.8843x; 2.8843x over previous
//
#include <hip/hip_runtime.h>

#define N_NODES 1024
#define C_CH    128
#define N_ELEM  10
#define K3      11
#define W3PM    1040                 // padded symmetric-cubic floats per slot
#define SU2OFF  49920                // float offset of SU2 region in ws (4*1040*12)

// ---------- kernel A0: element/channel-independent symmetrized U ----------
__global__ __launch_bounds__(256) void precompute_kernel(
    const float* __restrict__ U03, const float* __restrict__ U02,
    const float* __restrict__ U13, const float* __restrict__ U12,
    float* __restrict__ ws)
{
  const int t = blockIdx.x * 256 + threadIdx.x;
  if (t < 4160) {                    // SU3 rows: [m][j(padded 1040)][12]
    const int m = t / W3PM;
    const int j = t - m * W3PM;
    int a = 0, b = 0, off = 0;
    bool fnd = false;
    for (a = 0; a < 16 && !fnd; ++a) {
      for (b = 0; b <= a; ++b) {
        const int rl = ((b >> 2) + 1) << 2;
        if (j < off + rl) { fnd = true; break; }
        off += rl;
      }
      if (fnd) break;
    }
    const int cc = j - off;
    float out[12];
    #pragma unroll
    for (int k = 0; k < 12; ++k) out[k] = 0.f;
    if (cc <= b) {
      const float* U3 = (m == 0) ? U03 : (U13 + (size_t)(m - 1) * 45056);
      int bases[6]; int np = 0;
      if (a == b && b == cc) {
        bases[np++] = ((a * 16 + a) * 16 + a) * K3;
      } else if (a == b) {
        bases[np++] = ((a * 16 + a) * 16 + cc) * K3;
        bases[np++] = ((a * 16 + cc) * 16 + a) * K3;
        bases[np++] = ((cc * 16 + a) * 16 + a) * K3;
      } else if (b == cc) {
        bases[np++] = ((a * 16 + b) * 16 + b) * K3;
        bases[np++] = ((b * 16 + a) * 16 + b) * K3;
        bases[np++] = ((b * 16 + b) * 16 + a) * K3;
      } else {
        bases[np++] = ((a * 16 + b) * 16 + cc) * K3;
        bases[np++] = ((a * 16 + cc) * 16 + b) * K3;
        bases[np++] = ((b * 16 + a) * 16 + cc) * K3;
        bases[np++] = ((b * 16 + cc) * 16 + a) * K3;
        bases[np++] = ((cc * 16 + a) * 16 + b) * K3;
        bases[np++] = ((cc * 16 + b) * 16 + a) * K3;
      }
      for (int p = 0; p < np; ++p) {
        const float* src = U3 + bases[p];
        #pragma unroll
        for (int k = 0; k < K3; ++k) out[k] += src[k];
      }
    }
    float* dst = ws + (size_t)t * 12;
    *(float4*)&dst[0] = make_float4(out[0], out[1], out[2],  out[3]);
    *(float4*)&dst[4] = make_float4(out[4], out[5], out[6],  out[7]);
    *(float4*)&dst[8] = make_float4(out[8], out[9], out[10], out[11]);
  } else if (t < 4704) {             // SU2 rows: [m][q(136)][4]
    const int u = t - 4160;
    const int m = u / 136;
    const int q = u - m * 136;
    int a = 0, b = q;
    while (b > a) { b -= (a + 1); ++a; }
    const float* U2 = (m == 0) ? U02 : (U12 + (size_t)(m - 1) * 1024);
    const float* p1 = U2 + (a * 16 + b) * 4;
    float4 r = make_float4(p1[0], p1[1], p1[2], p1[3]);
    if (a != b) {
      const float* p2 = U2 + (b * 16 + a) * 4;
      r.x += p2[0]; r.y += p2[1]; r.z += p2[2]; r.w += p2[3];
    }
    ((float4*)(ws + SU2OFF))[u] = r;
  }
}

// ---------- kernel B: per-(e,c) contraction ----------
__global__ __launch_bounds__(256) void sym_contract_kernel(
    const float* __restrict__ node_feats,   // [N, C, 16]
    const float* __restrict__ node_attrs,   // [N, 10]
    const float* __restrict__ W03, const float* __restrict__ W02,
    const float* __restrict__ W01, const float* __restrict__ W13,
    const float* __restrict__ W12, const float* __restrict__ W11,
    const float* __restrict__ U01, const float* __restrict__ U11,
    const float* __restrict__ ws,           // SU3 | SU2
    float* __restrict__ feats_out)          // [N, C*4] pre-linear (= d_out)
{
  __shared__ float W3c[4 * W3PM];           // 16.6 KB
  __shared__ float T2c[4 * 136];
  __shared__ float T1s[64];
  __shared__ unsigned short nodelist[N_NODES];
  __shared__ float wrow[32];
  __shared__ int cnt;

  const int e   = blockIdx.x / C_CH;
  const int c   = blockIdx.x % C_CH;
  const int tid = threadIdx.x;

  if (tid == 0) cnt = 0;
  if (tid < 32) {
    float v;
    if (tid < 11)       v = W03[(e * K3 + tid) * C_CH + c];
    else if (tid < 15)  v = W02[(e * 4 + (tid - 11)) * C_CH + c];
    else if (tid == 15) v = W01[e * C_CH + c];
    else if (tid < 27)  v = W13[(e * K3 + (tid - 16)) * C_CH + c];
    else if (tid < 31)  v = W12[(e * 4 + (tid - 27)) * C_CH + c];
    else                v = W11[e * C_CH + c];
    wrow[tid] = v;
  }
  __syncthreads();

  // node list for this element
  for (int nd = tid; nd < N_NODES; nd += 256)
    if (node_attrs[nd * N_ELEM + e] > 0.5f)
      nodelist[atomicAdd(&cnt, 1)] = (unsigned short)nd;

  // --- W3c = SU3 . wk  (coalesced 48B rows, lane-consecutive LDS writes) ---
  for (int ms = 0; ms < 4; ++ms) {
    const int wb = (ms == 0) ? 0 : 16;
    const float w0 = wrow[wb],     w1 = wrow[wb + 1], w2 = wrow[wb + 2];
    const float w3 = wrow[wb + 3], w4 = wrow[wb + 4], w5 = wrow[wb + 5];
    const float w6 = wrow[wb + 6], w7 = wrow[wb + 7], w8 = wrow[wb + 8];
    const float w9 = wrow[wb + 9], wA = wrow[wb + 10];
    for (int j = tid; j < W3PM; j += 256) {
      const float* r = ws + ((size_t)ms * W3PM + j) * 12;
      const float4 r0 = *(const float4*)&r[0];
      const float4 r1 = *(const float4*)&r[4];
      const float4 r2 = *(const float4*)&r[8];
      float acc =       r0.x * w0;
      acc = fmaf(r0.y, w1, acc); acc = fmaf(r0.z, w2, acc);
      acc = fmaf(r0.w, w3, acc); acc = fmaf(r1.x, w4, acc);
      acc = fmaf(r1.y, w5, acc); acc = fmaf(r1.z, w6, acc);
      acc = fmaf(r1.w, w7, acc); acc = fmaf(r2.x, w8, acc);
      acc = fmaf(r2.y, w9, acc); acc = fmaf(r2.z, wA, acc);
      W3c[ms * W3PM + j] = acc;
    }
  }
  // --- T2c = SU2 . w2 ---
  const float4* SU2 = (const float4*)(ws + SU2OFF);
  for (int ms = 0; ms < 4; ++ms) {
    const int wb = (ms == 0) ? 11 : 27;
    const float q0 = wrow[wb], q1 = wrow[wb + 1], q2 = wrow[wb + 2], q3 = wrow[wb + 3];
    for (int q = tid; q < 136; q += 256) {
      const float4 r = SU2[ms * 136 + q];
      float acc = r.x * q0;
      acc = fmaf(r.y, q1, acc); acc = fmaf(r.z, q2, acc); acc = fmaf(r.w, q3, acc);
      T2c[ms * 136 + q] = acc;
    }
  }
  if (tid < 64) {
    const int mm = tid >> 4, i1 = tid & 15;
    T1s[tid] = (mm == 0) ? U01[i1] * wrow[15] : U11[(mm - 1) * 16 + i1] * wrow[31];
  }
  __syncthreads();

  // --- phase B: wave = m slot, lane = node; triangular Horner, dual chains ---
  const int m    = tid >> 6;
  const int lane = tid & 63;
  const float* W3m = W3c + m * W3PM;
  const float* T2m = T2c + m * 136;
  const float* T1m = T1s + m * 16;
  const int total = cnt;

  for (int base = 0; base < total; base += 64) {
    const int idx     = base + lane;
    const bool active = idx < total;
    const int nd = nodelist[active ? idx : 0];
    const float* xr = node_feats + ((size_t)nd * C_CH + c) * 16;
    float xs[16];                            // static-index only -> registers
    *(float4*)&xs[0]  = ((const float4*)xr)[0];
    *(float4*)&xs[4]  = ((const float4*)xr)[1];
    *(float4*)&xs[8]  = ((const float4*)xr)[2];
    *(float4*)&xs[12] = ((const float4*)xr)[3];

    float acc0 = 0.f, acc1 = 0.f;
    int woff = 0, tp = 0;                    // unroll-folded running offsets
    #pragma unroll
    for (int a = 0; a < 16; ++a) {
      float i1a = T1m[a], i1b = 0.f;         // dual chains over b
      #pragma unroll
      for (int b = 0; b <= a; ++b) {
        float in2 = T2m[tp];
        #pragma unroll
        for (int q = 0; q <= (b >> 2); ++q) {
          const float4 w4 = *(const float4*)&W3m[woff + 4 * q];   // broadcast
          in2 = fmaf(w4.x, xs[4 * q + 0], in2);
          in2 = fmaf(w4.y, xs[4 * q + 1], in2);
          in2 = fmaf(w4.z, xs[4 * q + 2], in2);
          in2 = fmaf(w4.w, xs[4 * q + 3], in2);
        }
        if (b & 1) i1b = fmaf(in2, xs[b], i1b);
        else       i1a = fmaf(in2, xs[b], i1a);
        woff += ((b >> 2) + 1) << 2;
        ++tp;
      }
      const float in1 = i1a + i1b;
      if (a & 1) acc1 = fmaf(in1, xs[a], acc1);
      else       acc0 = fmaf(in1, xs[a], acc0);
    }
    if (active)
      feats_out[(size_t)nd * 512 + c * 4 + m] = acc0 + acc1;
  }
}

__global__ __launch_bounds__(256) void linear_kernel(
    const float* __restrict__ sc,
    const float* __restrict__ lin0,
    const float* __restrict__ lin1,
    float* __restrict__ io)             // d_out, in-place per-row
{
  __shared__ float f[512];              // [c][m]
  const int b   = blockIdx.x;
  const int tid = threadIdx.x;
  const float* row = io + (size_t)b * 512;
  if (tid < 128) ((float4*)f)[tid] = ((const float4*)row)[tid];
  __syncthreads();
  const float inv_sqrt_c = 0.088388347648318447f;   // 1/sqrt(128)
  #pragma unroll
  for (int rep = 0; rep < 2; ++rep) {
    const int o = tid + rep * 256;
    float acc = 0.f;
    if (o < 128) {
      const int fo = o;
      #pragma unroll 4
      for (int ci = 0; ci < 128; ++ci) acc = fmaf(f[ci * 4], lin0[ci * 128 + fo], acc);
    } else {
      const int oo = o - 128;
      const int fo = oo / 3;
      const int dd = oo - fo * 3;
      #pragma unroll 4
      for (int ci = 0; ci < 128; ++ci) acc = fmaf(f[ci * 4 + 1 + dd], lin1[ci * 128 + fo], acc);
    }
    io[(size_t)b * 512 + o] = fmaf(acc, inv_sqrt_c, sc[(size_t)b * 512 + o]);
  }
}

extern "C" void kernel_launch(void* const* d_in, const int* in_sizes, int n_in,
                              void* d_out, int out_size, void* d_ws, size_t ws_size,
                              hipStream_t stream) {
  const float* node_feats = (const float*)d_in[0];
  const float* sc         = (const float*)d_in[1];
  const float* node_attrs = (const float*)d_in[2];
  const float* U01  = (const float*)d_in[3];
  const float* W01  = (const float*)d_in[4];
  const float* U02  = (const float*)d_in[5];
  const float* W02  = (const float*)d_in[6];
  const float* U03  = (const float*)d_in[7];
  const float* W03  = (const float*)d_in[8];
  const float* lin0 = (const float*)d_in[9];
  const float* U11  = (const float*)d_in[10];
  const float* W11  = (const float*)d_in[11];
  const float* U12  = (const float*)d_in[12];
  const float* W12  = (const float*)d_in[13];
  const float* U13  = (const float*)d_in[14];
  const float* W13  = (const float*)d_in[15];
  const float* lin1 = (const float*)d_in[16];
  float* out = (float*)d_out;
  float* ws  = (float*)d_ws;

  precompute_kernel<<<19, 256, 0, stream>>>(U03, U02, U13, U12, ws);
  sym_contract_kernel<<<N_ELEM * C_CH, 256, 0, stream>>>(
      node_feats, node_attrs,
      W03, W02, W01, W13, W12, W11, U01, U11, ws, out);
  linear_kernel<<<N_NODES, 256, 0, stream>>>(sc, lin0, lin1, out);
}